// Round 12
// baseline (89.728 us; speedup 1.0000x reference)
//
#include <hip/hip_runtime.h>
#include <stdint.h>
#include <math.h>

// Multiresolution hash encoding, 16 levels.
// grids = {4,5,6,9,12,15,21,27,36,48,63,84,111,147,194,255}
// kh = 256//grid, P = floor(256/kh).
// memset: mws = 0 (maxima workspace; image in [0,1) => max >= 0).
// K1 pool_single: 4-row bands (1024 blocks). Stage band in LDS + per-column
//     4-row max tier (cmax). 2 syncs, then read-only balanced task loop:
//     full-band cells (kh>=4) read cmax (kh reads), partial cells read simg.
//     kh in {2,4}: band-local -> plain store; else atomicMax (float>=0).
// K2 render: direct levels 13..15 (kh=1, identity bilinear) + LDS-tiled
//     bilinear levels 0..12; wave = 64 cols, 16 rows/wave (64x64 tile),
//     cached x-interpolated row pair (reload only on source-row change).

#define NLVL 16
#define NB   16

typedef float nvec4 __attribute__((ext_vector_type(4)));   // native vec for nontemporal

__constant__ int   c_P[NLVL]   = {4,5,6,9,12,15,21,28,36,51,64,85,128,256,256,256};
__constant__ float c_G[NLVL]   = {4.f,5.f,6.f,9.f,12.f,15.f,21.f,27.f,36.f,48.f,63.f,84.f,111.f,147.f,194.f,255.f};
__constant__ int   c_CUM[14]   = {0,16,41,77,158,302,527,968,1752,3048,5649,9745,16970,33354};

#define CELLS_PB   33354                 // cells/batch, levels 0..12
#define CELLS_TOT  (CELLS_PB*NB)         // 533664
#define MWS_FLOATS (CELLS_TOT*3)         // 1600992
#define POOL_BLOCKS (NB*64)              // 1024: (batch, 4-row band)
#define DIR_BLOCKS  1024
#define TILE_BLOCKS (13*16*16)           // 3328
#define K2_BLOCKS   (DIR_BLOCKS + TILE_BLOCKS)

__device__ __forceinline__ uint32_t hash3(float m0, float m1, float m2, float g) {
    uint32_t v0 = (uint32_t)(int)(m0 * g);
    uint32_t v1 = (uint32_t)(int)(m1 * g);
    uint32_t v2 = (uint32_t)(int)(m2 * g);
    return (v0 ^ (v1 * 2654435761u) ^ (v2 * 805459861u)) & 0xFFFFu;
}

__device__ __forceinline__ void nt_store4(float* p, float a, float b, float c, float d) {
    nvec4 v; v.x = a; v.y = b; v.z = c; v.w = d;
    __builtin_nontemporal_store(v, (nvec4*)p);
}

// ---- K1: single-pass pooling, 4-row bands, tiered column maxima ----
__global__ __launch_bounds__(256) void pool_single(const float* __restrict__ img,
                                                   unsigned int* __restrict__ mws)
{
    static constexpr int K_P[13]   = {4,5,6,9,12,15,21,28,36,51,64,85,128};
    static constexpr int K_KH[13]  = {64,51,42,28,21,17,12,9,7,5,4,3,2};
    static constexpr int K_CUM[13] = {0,16,41,77,158,302,527,968,1752,3048,5649,9745,16970};

    __shared__ float simg[3][4][256];
    __shared__ float cmax[3][256];

    int b    = blockIdx.x >> 6;
    int band = blockIdx.x & 63;
    int y0   = band * 4;

    const float* base = img + (size_t)b * 196608 + (size_t)y0 * 256;
    for (int t = threadIdx.x; t < 768; t += 256) {   // 3ch x 4rows x 64 float4
        int ch  = t >> 8;
        int rem = t & 255;
        int row = rem >> 6, cg = rem & 63;
        float4 v = *(const float4*)(base + (size_t)ch * 65536 + row * 256 + cg * 4);
        int c4 = cg << 2;
        simg[ch][row][c4 + 0] = v.x;
        simg[ch][row][c4 + 1] = v.y;
        simg[ch][row][c4 + 2] = v.z;
        simg[ch][row][c4 + 3] = v.w;
    }
    __syncthreads();

    {
        int x = threadIdx.x;
#pragma unroll
        for (int ch = 0; ch < 3; ++ch)
            cmax[ch][x] = fmaxf(fmaxf(simg[ch][0][x], simg[ch][1][x]),
                                fmaxf(simg[ch][2][x], simg[ch][3][x]));
    }
    __syncthreads();

#pragma unroll
    for (int lvl = 0; lvl < 13; ++lvl) {
        const int kh = K_KH[lvl], P = K_P[lvl];
        int nr0 = y0 / kh;
        int nr1 = (y0 + 3) / kh; if (nr1 > P - 1) nr1 = P - 1;
        int cnt = (nr1 - nr0 + 1) * P;
        for (int t = threadIdx.x; t < cnt; t += 256) {
            int dcr = t / P;
            int cx  = t - dcr * P;
            int cr  = nr0 + dcr;
            int rlo = cr * kh;      if (rlo < y0) rlo = y0;
            int rhi = cr * kh + kh; if (rhi > y0 + 4) rhi = y0 + 4;
            int cA = cx * kh, cB = cA + kh;
            float m0 = -INFINITY, m1 = -INFINITY, m2 = -INFINITY;
            if (rlo == y0 && rhi == y0 + 4) {
                for (int c = cA; c < cB; ++c) {
                    m0 = fmaxf(m0, cmax[0][c]);
                    m1 = fmaxf(m1, cmax[1][c]);
                    m2 = fmaxf(m2, cmax[2][c]);
                }
            } else {
                for (int r = rlo; r < rhi; ++r) {
                    int rr = r - y0;
                    for (int c = cA; c < cB; ++c) {
                        m0 = fmaxf(m0, simg[0][rr][c]);
                        m1 = fmaxf(m1, simg[1][rr][c]);
                        m2 = fmaxf(m2, simg[2][rr][c]);
                    }
                }
            }
            int idx = K_CUM[lvl] * NB + b * P * P + cr * P + cx;
            if (kh == 2 || kh == 4) {            // cell fully inside this band
                mws[idx]                 = __float_as_uint(m0);
                mws[idx + CELLS_TOT]     = __float_as_uint(m1);
                mws[idx + 2 * CELLS_TOT] = __float_as_uint(m2);
            } else {
                atomicMax(&mws[idx],                 __float_as_uint(m0));
                atomicMax(&mws[idx + CELLS_TOT],     __float_as_uint(m1));
                atomicMax(&mws[idx + 2 * CELLS_TOT], __float_as_uint(m2));
            }
        }
    }
}

// ---- K2: direct levels 13..15 + LDS-tiled bilinear (hash+gather fused) ----
// src = ((2o+1)*P - 256)/512 : exact int; frac exact in fp32.
__global__ __launch_bounds__(256) void render(const float* __restrict__ img,
                                              const float* __restrict__ tab,
                                              const float* __restrict__ mws,
                                              float* __restrict__ out)
{
    __shared__ float4 s[34 * 34];
    if (blockIdx.x < DIR_BLOCKS) {
        int t = blockIdx.x * 256 + threadIdx.x;     // 262144 total
        int b = t >> 14;
        int pix0 = (t & 16383) << 2;
        const float* p = img + (size_t)b * 196608 + pix0;
        float4 i0 = *(const float4*)p;
        float4 i1 = *(const float4*)(p + 65536);
        float4 i2 = *(const float4*)(p + 131072);
#pragma unroll
        for (int lvl = 13; lvl < 16; ++lvl) {
            float g = c_G[lvl];
            const float* T = tab + (size_t)lvl * 196608;
            uint32_t g0 = hash3(i0.x, i1.x, i2.x, g);
            uint32_t g1 = hash3(i0.y, i1.y, i2.y, g);
            uint32_t g2 = hash3(i0.z, i1.z, i2.z, g);
            uint32_t g3 = hash3(i0.w, i1.w, i2.w, g);
            float3 f0 = *(const float3*)(T + g0 * 3);
            float3 f1 = *(const float3*)(T + g1 * 3);
            float3 f2 = *(const float3*)(T + g2 * 3);
            float3 f3 = *(const float3*)(T + g3 * 3);
            float* ob = out + ((size_t)b * 48 + 3 * lvl) * 65536 + pix0;
            nt_store4(ob,            f0.x, f1.x, f2.x, f3.x);
            nt_store4(ob + 65536,    f0.y, f1.y, f2.y, f3.y);
            nt_store4(ob + 131072,   f0.z, f1.z, f2.z, f3.z);
        }
        return;
    }

    int blk   = blockIdx.x - DIR_BLOCKS;
    int tile  = blk & 15;
    int plane = blk >> 4;            // 0..207
    int lvl   = plane >> 4;
    int b     = plane & 15;
    int P     = c_P[lvl];
    int yt0   = (tile >> 2) * 64;
    int xt0   = (tile & 3) * 64;

    int nlo  = ((2 * yt0 + 1) * P - 256) >> 9;
    int r_lo = nlo < 0 ? 0 : (nlo > P - 1 ? P - 1 : nlo);
    int nhi  = (((2 * (yt0 + 63) + 1) * P - 256) >> 9) + 1;
    int r_hi = nhi < 0 ? 0 : (nhi > P - 1 ? P - 1 : nhi);
    int mlo  = ((2 * xt0 + 1) * P - 256) >> 9;
    int c_lo = mlo < 0 ? 0 : (mlo > P - 1 ? P - 1 : mlo);
    int mhi  = (((2 * (xt0 + 63) + 1) * P - 256) >> 9) + 1;
    int c_hi = mhi < 0 ? 0 : (mhi > P - 1 ? P - 1 : mhi);
    int span_y = r_hi - r_lo + 1;
    int span_x = c_hi - c_lo + 1;

    // stage: read maxima, hash, gather table feature per window cell
    int planebase = c_CUM[lvl] * NB + b * P * P;
    const float* T = tab + (size_t)lvl * 196608;
    float gmul = c_G[lvl];
    int n = span_y * span_x;
    for (int t = threadIdx.x; t < n; t += 256) {
        int r = t / span_x, c = t - r * span_x;
        int idx = planebase + (r_lo + r) * P + c_lo + c;
        float m0 = mws[idx];
        float m1 = mws[idx + CELLS_TOT];
        float m2 = mws[idx + 2 * CELLS_TOT];
        uint32_t g = hash3(m0, m1, m2, gmul);
        float3 tv = *(const float3*)(T + g * 3);
        float4 fv; fv.x = tv.x; fv.y = tv.y; fv.z = tv.z; fv.w = 0.f;
        s[t] = fv;
    }
    __syncthreads();

    int lane = threadIdx.x & 63;
    int w    = threadIdx.x >> 6;
    int x    = xt0 + lane;

    int numx = (2 * x + 1) * P - 256;
    int ix0  = numx >> 9;
    float fx = (float)(numx & 511) * (1.0f / 512.0f);
    int ix1;
    if (ix0 < 0)           { ix0 = 0;     ix1 = 0;     fx = 0.f; }
    else if (ix0 >= P - 1) { ix0 = P - 1; ix1 = P - 1; fx = 0.f; }
    else                   { ix1 = ix0 + 1; }
    int cA = ix0 - c_lo, cB = ix1 - c_lo;
    float wx0 = 1.f - fx, wx1 = fx;

    int cur0 = -1, cur1 = -1;
    float r0x = 0.f, r0y = 0.f, r0z = 0.f;
    float r1x = 0.f, r1y = 0.f, r1z = 0.f;
    float* obase = out + ((size_t)b * 48 + 3 * lvl) * 65536 + x;

    for (int k = 0; k < 16; ++k) {
        int y = yt0 + w * 16 + k;
        int numy = (2 * y + 1) * P - 256;
        int iy0  = numy >> 9;
        float fy = (float)(numy & 511) * (1.0f / 512.0f);
        int iy1;
        if (iy0 < 0)           { iy0 = 0;     iy1 = 0;     fy = 0.f; }
        else if (iy0 >= P - 1) { iy0 = P - 1; iy1 = P - 1; fy = 0.f; }
        else                   { iy1 = iy0 + 1; }

        if (iy0 != cur0) {
            if (iy0 == cur1) { r0x = r1x; r0y = r1y; r0z = r1z; }
            else {
                const float4* p = s + (iy0 - r_lo) * span_x;
                float4 a = p[cA], q = p[cB];
                r0x = wx0 * a.x + wx1 * q.x;
                r0y = wx0 * a.y + wx1 * q.y;
                r0z = wx0 * a.z + wx1 * q.z;
            }
            cur0 = iy0;
        }
        if (iy1 != cur1) {
            const float4* p = s + (iy1 - r_lo) * span_x;
            float4 a = p[cA], q = p[cB];
            r1x = wx0 * a.x + wx1 * q.x;
            r1y = wx0 * a.y + wx1 * q.y;
            r1z = wx0 * a.z + wx1 * q.z;
            cur1 = iy1;
        }

        float wy0 = 1.f - fy, wy1 = fy;
        float* o = obase + (size_t)y * 256;
        __builtin_nontemporal_store(wy0 * r0x + wy1 * r1x, o);
        __builtin_nontemporal_store(wy0 * r0y + wy1 * r1y, o + 65536);
        __builtin_nontemporal_store(wy0 * r0z + wy1 * r1z, o + 131072);
    }
}

extern "C" void kernel_launch(void* const* d_in, const int* in_sizes, int n_in,
                              void* d_out, int out_size, void* d_ws, size_t ws_size,
                              hipStream_t stream)
{
    const float* img = (const float*)d_in[0];   // (16,3,256,256) f32
    const float* tab = (const float*)d_in[1];   // (16,65536,3) f32
    float* out = (float*)d_out;                 // (16,48,256,256) f32
    float* mws = (float*)d_ws;                  // 1,600,992 f32 = 6.4 MB

    (void)hipMemsetAsync(mws, 0, (size_t)MWS_FLOATS * sizeof(float), stream);
    hipLaunchKernelGGL(pool_single, dim3(POOL_BLOCKS), dim3(256), 0, stream, img, (unsigned int*)mws);
    hipLaunchKernelGGL(render,      dim3(K2_BLOCKS), dim3(256), 0, stream, img, tab, mws, out);
}

// Round 13
// 88.041 us; speedup vs baseline: 1.0192x; 1.0192x over previous
//
#include <hip/hip_runtime.h>
#include <stdint.h>
#include <math.h>

// Multiresolution hash encoding, 16 levels.
// grids = {4,5,6,9,12,15,21,27,36,48,63,84,111,147,194,255}
// kh = 256//grid, P = floor(256/kh).
// memset: mws = 0 (maxima workspace; image in [0,1) => max >= 0).
// K1 pool_single: 4-row bands (1024 blocks), tiered cmax, 2 syncs/block,
//     read-only balanced task loop; kh in {2,4} band-local -> plain store,
//     else atomicMax (float>=0).
// K2 render: R9 structure: direct levels 13..15 + LDS-tiled bilinear levels
//     0..12 (hash+gather fused into staging), 16 px/thread, float4 stores.

#define NLVL 16
#define NB   16

__constant__ int   c_P[NLVL]   = {4,5,6,9,12,15,21,28,36,51,64,85,128,256,256,256};
__constant__ float c_G[NLVL]   = {4.f,5.f,6.f,9.f,12.f,15.f,21.f,27.f,36.f,48.f,63.f,84.f,111.f,147.f,194.f,255.f};
__constant__ int   c_CUM[14]   = {0,16,41,77,158,302,527,968,1752,3048,5649,9745,16970,33354};

#define CELLS_PB   33354                 // cells/batch, levels 0..12
#define CELLS_TOT  (CELLS_PB*NB)         // 533664
#define MWS_FLOATS (CELLS_TOT*3)         // 1600992
#define POOL_BLOCKS (NB*64)              // 1024: (batch, 4-row band)
#define DIR_BLOCKS  1024
#define TILE_BLOCKS (13*16*16)           // 3328
#define K2_BLOCKS   (DIR_BLOCKS + TILE_BLOCKS)

__device__ __forceinline__ uint32_t hash3(float m0, float m1, float m2, float g) {
    uint32_t v0 = (uint32_t)(int)(m0 * g);
    uint32_t v1 = (uint32_t)(int)(m1 * g);
    uint32_t v2 = (uint32_t)(int)(m2 * g);
    return (v0 ^ (v1 * 2654435761u) ^ (v2 * 805459861u)) & 0xFFFFu;
}

// ---- K1: single-pass pooling, 4-row bands, tiered column maxima ----
__global__ __launch_bounds__(256) void pool_single(const float* __restrict__ img,
                                                   unsigned int* __restrict__ mws)
{
    static constexpr int K_P[13]   = {4,5,6,9,12,15,21,28,36,51,64,85,128};
    static constexpr int K_KH[13]  = {64,51,42,28,21,17,12,9,7,5,4,3,2};
    static constexpr int K_CUM[13] = {0,16,41,77,158,302,527,968,1752,3048,5649,9745,16970};

    __shared__ float simg[3][4][256];
    __shared__ float cmax[3][256];

    int b    = blockIdx.x >> 6;
    int band = blockIdx.x & 63;
    int y0   = band * 4;

    const float* base = img + (size_t)b * 196608 + (size_t)y0 * 256;
    for (int t = threadIdx.x; t < 768; t += 256) {   // 3ch x 4rows x 64 float4
        int ch  = t >> 8;
        int rem = t & 255;
        int row = rem >> 6, cg = rem & 63;
        float4 v = *(const float4*)(base + (size_t)ch * 65536 + row * 256 + cg * 4);
        int c4 = cg << 2;
        simg[ch][row][c4 + 0] = v.x;
        simg[ch][row][c4 + 1] = v.y;
        simg[ch][row][c4 + 2] = v.z;
        simg[ch][row][c4 + 3] = v.w;
    }
    __syncthreads();

    {
        int x = threadIdx.x;
#pragma unroll
        for (int ch = 0; ch < 3; ++ch)
            cmax[ch][x] = fmaxf(fmaxf(simg[ch][0][x], simg[ch][1][x]),
                                fmaxf(simg[ch][2][x], simg[ch][3][x]));
    }
    __syncthreads();

#pragma unroll
    for (int lvl = 0; lvl < 13; ++lvl) {
        const int kh = K_KH[lvl], P = K_P[lvl];
        int nr0 = y0 / kh;
        int nr1 = (y0 + 3) / kh; if (nr1 > P - 1) nr1 = P - 1;
        int cnt = (nr1 - nr0 + 1) * P;
        for (int t = threadIdx.x; t < cnt; t += 256) {
            int dcr = t / P;
            int cx  = t - dcr * P;
            int cr  = nr0 + dcr;
            int rlo = cr * kh;      if (rlo < y0) rlo = y0;
            int rhi = cr * kh + kh; if (rhi > y0 + 4) rhi = y0 + 4;
            int cA = cx * kh, cB = cA + kh;
            float m0 = -INFINITY, m1 = -INFINITY, m2 = -INFINITY;
            if (rlo == y0 && rhi == y0 + 4) {
                for (int c = cA; c < cB; ++c) {
                    m0 = fmaxf(m0, cmax[0][c]);
                    m1 = fmaxf(m1, cmax[1][c]);
                    m2 = fmaxf(m2, cmax[2][c]);
                }
            } else {
                for (int r = rlo; r < rhi; ++r) {
                    int rr = r - y0;
                    for (int c = cA; c < cB; ++c) {
                        m0 = fmaxf(m0, simg[0][rr][c]);
                        m1 = fmaxf(m1, simg[1][rr][c]);
                        m2 = fmaxf(m2, simg[2][rr][c]);
                    }
                }
            }
            int idx = K_CUM[lvl] * NB + b * P * P + cr * P + cx;
            if (kh == 2 || kh == 4) {            // cell fully inside this band
                mws[idx]                 = __float_as_uint(m0);
                mws[idx + CELLS_TOT]     = __float_as_uint(m1);
                mws[idx + 2 * CELLS_TOT] = __float_as_uint(m2);
            } else {
                atomicMax(&mws[idx],                 __float_as_uint(m0));
                atomicMax(&mws[idx + CELLS_TOT],     __float_as_uint(m1));
                atomicMax(&mws[idx + 2 * CELLS_TOT], __float_as_uint(m2));
            }
        }
    }
}

// ---- K2: direct levels 13..15 + LDS-tiled bilinear (hash+gather fused) ----
// src = ((2o+1)*P - 256)/512 : exact int; frac exact in fp32.
__global__ __launch_bounds__(256) void render(const float* __restrict__ img,
                                              const float* __restrict__ tab,
                                              const float* __restrict__ mws,
                                              float* __restrict__ out)
{
    __shared__ float4 s[34 * 34];
    if (blockIdx.x < DIR_BLOCKS) {
        int t = blockIdx.x * 256 + threadIdx.x;     // 262144 total
        int b = t >> 14;
        int pix0 = (t & 16383) << 2;
        const float* p = img + (size_t)b * 196608 + pix0;
        float4 i0 = *(const float4*)p;
        float4 i1 = *(const float4*)(p + 65536);
        float4 i2 = *(const float4*)(p + 131072);
#pragma unroll
        for (int lvl = 13; lvl < 16; ++lvl) {
            float g = c_G[lvl];
            const float* T = tab + (size_t)lvl * 196608;
            uint32_t g0 = hash3(i0.x, i1.x, i2.x, g);
            uint32_t g1 = hash3(i0.y, i1.y, i2.y, g);
            uint32_t g2 = hash3(i0.z, i1.z, i2.z, g);
            uint32_t g3 = hash3(i0.w, i1.w, i2.w, g);
            float3 f0 = *(const float3*)(T + g0 * 3);
            float3 f1 = *(const float3*)(T + g1 * 3);
            float3 f2 = *(const float3*)(T + g2 * 3);
            float3 f3 = *(const float3*)(T + g3 * 3);
            float4 o0, o1, o2;
            o0.x = f0.x; o1.x = f0.y; o2.x = f0.z;
            o0.y = f1.x; o1.y = f1.y; o2.y = f1.z;
            o0.z = f2.x; o1.z = f2.y; o2.z = f2.z;
            o0.w = f3.x; o1.w = f3.y; o2.w = f3.z;
            float* ob = out + ((size_t)b * 48 + 3 * lvl) * 65536 + pix0;
            *(float4*)ob            = o0;
            *(float4*)(ob + 65536)  = o1;
            *(float4*)(ob + 131072) = o2;
        }
        return;
    }

    int blk   = blockIdx.x - DIR_BLOCKS;
    int tile  = blk & 15;
    int plane = blk >> 4;            // 0..207
    int lvl   = plane >> 4;
    int b     = plane & 15;
    int P     = c_P[lvl];
    int yt0   = (tile >> 2) * 64;
    int xt0   = (tile & 3) * 64;

    int nlo  = ((2 * yt0 + 1) * P - 256) >> 9;
    int r_lo = nlo < 0 ? 0 : (nlo > P - 1 ? P - 1 : nlo);
    int nhi  = (((2 * (yt0 + 63) + 1) * P - 256) >> 9) + 1;
    int r_hi = nhi < 0 ? 0 : (nhi > P - 1 ? P - 1 : nhi);
    int mlo  = ((2 * xt0 + 1) * P - 256) >> 9;
    int c_lo = mlo < 0 ? 0 : (mlo > P - 1 ? P - 1 : mlo);
    int mhi  = (((2 * (xt0 + 63) + 1) * P - 256) >> 9) + 1;
    int c_hi = mhi < 0 ? 0 : (mhi > P - 1 ? P - 1 : mhi);
    int span_y = r_hi - r_lo + 1;
    int span_x = c_hi - c_lo + 1;

    // stage: read maxima, hash, gather table feature per window cell
    int planebase = c_CUM[lvl] * NB + b * P * P;
    const float* T = tab + (size_t)lvl * 196608;
    float gmul = c_G[lvl];
    int n = span_y * span_x;
    for (int t = threadIdx.x; t < n; t += 256) {
        int r = t / span_x, c = t - r * span_x;
        int idx = planebase + (r_lo + r) * P + c_lo + c;
        float m0 = mws[idx];
        float m1 = mws[idx + CELLS_TOT];
        float m2 = mws[idx + 2 * CELLS_TOT];
        uint32_t g = hash3(m0, m1, m2, gmul);
        float3 tv = *(const float3*)(T + g * 3);
        float4 fv; fv.x = tv.x; fv.y = tv.y; fv.z = tv.z; fv.w = 0.f;
        s[t] = fv;
    }
    __syncthreads();

    int lane = threadIdx.x & 63;
    int w    = threadIdx.x >> 6;
    int xq   = lane & 15;
    int rg   = lane >> 4;
    int xb   = xt0 + xq * 4;

    int ix0t[4], ix1t[4]; float wx1t[4];
#pragma unroll
    for (int j = 0; j < 4; ++j) {
        int numx = (2 * (xb + j) + 1) * P - 256;
        int ix0  = numx >> 9;
        float fx = (float)(numx & 511) * (1.0f / 512.0f);
        int ix1;
        if (ix0 < 0)           { ix0 = 0;     ix1 = 0;     fx = 0.f; }
        else if (ix0 >= P - 1) { ix0 = P - 1; ix1 = P - 1; fx = 0.f; }
        else                   { ix1 = ix0 + 1; }
        ix0t[j] = ix0 - c_lo; ix1t[j] = ix1 - c_lo; wx1t[j] = fx;
    }

#pragma unroll
    for (int k = 0; k < 4; ++k) {
        int y = yt0 + w * 16 + rg * 4 + k;
        int numy = (2 * y + 1) * P - 256;
        int iy0  = numy >> 9;
        float fy = (float)(numy & 511) * (1.0f / 512.0f);
        int iy1;
        if (iy0 < 0)           { iy0 = 0;     iy1 = 0;     fy = 0.f; }
        else if (iy0 >= P - 1) { iy0 = P - 1; iy1 = P - 1; fy = 0.f; }
        else                   { iy1 = iy0 + 1; }
        const float4* p0 = s + (iy0 - r_lo) * span_x;
        const float4* p1 = s + (iy1 - r_lo) * span_x;
        float wy1 = fy, wy0 = 1.f - fy;

        float v[3][4];
#pragma unroll
        for (int j = 0; j < 4; ++j) {
            float wx1 = wx1t[j], wx0 = 1.f - wx1;
            float4 t00 = p0[ix0t[j]];
            float4 t01 = p0[ix1t[j]];
            float4 t10 = p1[ix0t[j]];
            float4 t11 = p1[ix1t[j]];
            v[0][j] = wy0 * (wx0 * t00.x + wx1 * t01.x) + wy1 * (wx0 * t10.x + wx1 * t11.x);
            v[1][j] = wy0 * (wx0 * t00.y + wx1 * t01.y) + wy1 * (wx0 * t10.y + wx1 * t11.y);
            v[2][j] = wy0 * (wx0 * t00.z + wx1 * t01.z) + wy1 * (wx0 * t10.z + wx1 * t11.z);
        }
        float* o = out + ((size_t)b * 48 + 3 * lvl) * 65536 + (size_t)y * 256 + xb;
#pragma unroll
        for (int c = 0; c < 3; ++c) {
            float4 q; q.x = v[c][0]; q.y = v[c][1]; q.z = v[c][2]; q.w = v[c][3];
            *(float4*)(o + (size_t)c * 65536) = q;
        }
    }
}

extern "C" void kernel_launch(void* const* d_in, const int* in_sizes, int n_in,
                              void* d_out, int out_size, void* d_ws, size_t ws_size,
                              hipStream_t stream)
{
    const float* img = (const float*)d_in[0];   // (16,3,256,256) f32
    const float* tab = (const float*)d_in[1];   // (16,65536,3) f32
    float* out = (float*)d_out;                 // (16,48,256,256) f32
    float* mws = (float*)d_ws;                  // 1,600,992 f32 = 6.4 MB

    (void)hipMemsetAsync(mws, 0, (size_t)MWS_FLOATS * sizeof(float), stream);
    hipLaunchKernelGGL(pool_single, dim3(POOL_BLOCKS), dim3(256), 0, stream, img, (unsigned int*)mws);
    hipLaunchKernelGGL(render,      dim3(K2_BLOCKS), dim3(256), 0, stream, img, tab, mws, out);
}

// Round 14
// 76.157 us; speedup vs baseline: 1.1782x; 1.1560x over previous
//
#include <hip/hip_runtime.h>
#include <stdint.h>
#include <math.h>

// Multiresolution hash encoding, 16 levels.
// grids = {4,5,6,9,12,15,21,27,36,48,63,84,111,147,194,255}
// kh = 256//grid, P = floor(256/kh).
// memset: mws = 0 (maxima workspace; image in [0,1) => max >= 0).
// K1 fused: blocks [0,512)    = R9 pooling (8-row bands, LDS stage, atomicMax)
//           blocks [512,1536) = levels 13..15 direct (kh=1, identity bilinear)
//           (independent work; direct hides under pool's runtime)
// K2: LDS-tiled bilinear levels 0..12, hash+gather fused into staging,
//     16 px/thread, float4 stores.  (R9 structure, byte-identical math)

#define NLVL 16
#define NB   16

__constant__ int   c_P[NLVL]   = {4,5,6,9,12,15,21,28,36,51,64,85,128,256,256,256};
__constant__ float c_G[NLVL]   = {4.f,5.f,6.f,9.f,12.f,15.f,21.f,27.f,36.f,48.f,63.f,84.f,111.f,147.f,194.f,255.f};
__constant__ int   c_CUM[14]   = {0,16,41,77,158,302,527,968,1752,3048,5649,9745,16970,33354};

#define CELLS_PB   33354                 // cells/batch, levels 0..12
#define CELLS_TOT  (CELLS_PB*NB)         // 533664
#define MWS_FLOATS (CELLS_TOT*3)         // 1600992
#define POOL_BLOCKS (NB*32)              // 512: (batch, 8-row band)
#define DIR_BLOCKS  1024
#define K1_BLOCKS   (POOL_BLOCKS + DIR_BLOCKS)   // 1536
#define TILE_BLOCKS (13*16*16)           // 3328

__device__ __forceinline__ uint32_t hash3(float m0, float m1, float m2, float g) {
    uint32_t v0 = (uint32_t)(int)(m0 * g);
    uint32_t v1 = (uint32_t)(int)(m1 * g);
    uint32_t v2 = (uint32_t)(int)(m2 * g);
    return (v0 ^ (v1 * 2654435761u) ^ (v2 * 805459861u)) & 0xFFFFu;
}

// ---- K1: fused pooling (R9 8-row bands) + direct levels 13..15 ----
__global__ __launch_bounds__(256) void pool_direct(const float* __restrict__ img,
                                                   const float* __restrict__ tab,
                                                   unsigned int* __restrict__ mws,
                                                   float* __restrict__ out)
{
    static constexpr int K_P[13]   = {4,5,6,9,12,15,21,28,36,51,64,85,128};
    static constexpr int K_KH[13]  = {64,51,42,28,21,17,12,9,7,5,4,3,2};
    static constexpr int K_CUM[13] = {0,16,41,77,158,302,527,968,1752,3048,5649,9745,16970};

    __shared__ float simg[3][8][256];
    __shared__ float colbuf[3][256];

    if (blockIdx.x >= POOL_BLOCKS) {
        // direct path, levels 13..15: identity bilinear, 4 px/thread
        int t = (blockIdx.x - POOL_BLOCKS) * 256 + threadIdx.x;   // 262144 total
        int b = t >> 14;
        int pix0 = (t & 16383) << 2;
        const float* p = img + (size_t)b * 196608 + pix0;
        float4 i0 = *(const float4*)p;
        float4 i1 = *(const float4*)(p + 65536);
        float4 i2 = *(const float4*)(p + 131072);
#pragma unroll
        for (int lvl = 13; lvl < 16; ++lvl) {
            float g = c_G[lvl];
            const float* T = tab + (size_t)lvl * 196608;
            uint32_t g0 = hash3(i0.x, i1.x, i2.x, g);
            uint32_t g1 = hash3(i0.y, i1.y, i2.y, g);
            uint32_t g2 = hash3(i0.z, i1.z, i2.z, g);
            uint32_t g3 = hash3(i0.w, i1.w, i2.w, g);
            float3 f0 = *(const float3*)(T + g0 * 3);
            float3 f1 = *(const float3*)(T + g1 * 3);
            float3 f2 = *(const float3*)(T + g2 * 3);
            float3 f3 = *(const float3*)(T + g3 * 3);
            float4 o0, o1, o2;
            o0.x = f0.x; o1.x = f0.y; o2.x = f0.z;
            o0.y = f1.x; o1.y = f1.y; o2.y = f1.z;
            o0.z = f2.x; o1.z = f2.y; o2.z = f2.z;
            o0.w = f3.x; o1.w = f3.y; o2.w = f3.z;
            float* ob = out + ((size_t)b * 48 + 3 * lvl) * 65536 + pix0;
            *(float4*)ob            = o0;
            *(float4*)(ob + 65536)  = o1;
            *(float4*)(ob + 131072) = o2;
        }
        return;
    }

    // pool path: R9 8-row band
    int b    = blockIdx.x >> 5;
    int band = blockIdx.x & 31;
    int y0   = band * 8;

    const float* base = img + (size_t)b * 196608 + (size_t)y0 * 256;
    for (int t = threadIdx.x; t < 1536; t += 256) {      // 1536 float4 = 3ch x 8rows x 256
        int ch = t >> 9;
        int r  = t & 511;
        float4 v = *(const float4*)(base + (size_t)ch * 65536 + r * 4);
        int row = r >> 6, c4 = (r & 63) << 2;
        simg[ch][row][c4 + 0] = v.x;
        simg[ch][row][c4 + 1] = v.y;
        simg[ch][row][c4 + 2] = v.z;
        simg[ch][row][c4 + 3] = v.w;
    }
    __syncthreads();

    int x = threadIdx.x;
#pragma unroll
    for (int lvl = 0; lvl < 13; ++lvl) {
        const int kh = K_KH[lvl], P = K_P[lvl];
        int nr0 = y0 / kh;
        int nr1 = (y0 + 7) / kh; if (nr1 > P - 1) nr1 = P - 1;
        for (int cr = nr0; cr <= nr1; ++cr) {
            int rlo = cr * kh;      if (rlo < y0) rlo = y0;
            int rhi = cr * kh + kh; if (rhi > y0 + 8) rhi = y0 + 8;
            float p0 = -INFINITY, p1 = -INFINITY, p2 = -INFINITY;
            for (int r = rlo; r < rhi; ++r) {
                int rr = r - y0;
                p0 = fmaxf(p0, simg[0][rr][x]);
                p1 = fmaxf(p1, simg[1][rr][x]);
                p2 = fmaxf(p2, simg[2][rr][x]);
            }
            colbuf[0][x] = p0; colbuf[1][x] = p1; colbuf[2][x] = p2;
            __syncthreads();
            if (x < P) {
                float q0 = -INFINITY, q1 = -INFINITY, q2 = -INFINITY;
                for (int c = x * kh; c < x * kh + kh; ++c) {
                    q0 = fmaxf(q0, colbuf[0][c]);
                    q1 = fmaxf(q1, colbuf[1][c]);
                    q2 = fmaxf(q2, colbuf[2][c]);
                }
                int idx = K_CUM[lvl] * NB + b * P * P + cr * P + x;
                atomicMax(&mws[idx],                 __float_as_uint(q0));
                atomicMax(&mws[idx + CELLS_TOT],     __float_as_uint(q1));
                atomicMax(&mws[idx + 2 * CELLS_TOT], __float_as_uint(q2));
            }
            __syncthreads();
        }
    }
}

// ---- K2: LDS-tiled bilinear levels 0..12 (hash+gather fused) ----
// src = ((2o+1)*P - 256)/512 : exact int; frac exact in fp32.
__global__ __launch_bounds__(256) void render_tiles(const float* __restrict__ tab,
                                                    const float* __restrict__ mws,
                                                    float* __restrict__ out)
{
    __shared__ float4 s[34 * 34];
    int blk   = blockIdx.x;
    int tile  = blk & 15;
    int plane = blk >> 4;            // 0..207
    int lvl   = plane >> 4;
    int b     = plane & 15;
    int P     = c_P[lvl];
    int yt0   = (tile >> 2) * 64;
    int xt0   = (tile & 3) * 64;

    int nlo  = ((2 * yt0 + 1) * P - 256) >> 9;
    int r_lo = nlo < 0 ? 0 : (nlo > P - 1 ? P - 1 : nlo);
    int nhi  = (((2 * (yt0 + 63) + 1) * P - 256) >> 9) + 1;
    int r_hi = nhi < 0 ? 0 : (nhi > P - 1 ? P - 1 : nhi);
    int mlo  = ((2 * xt0 + 1) * P - 256) >> 9;
    int c_lo = mlo < 0 ? 0 : (mlo > P - 1 ? P - 1 : mlo);
    int mhi  = (((2 * (xt0 + 63) + 1) * P - 256) >> 9) + 1;
    int c_hi = mhi < 0 ? 0 : (mhi > P - 1 ? P - 1 : mhi);
    int span_y = r_hi - r_lo + 1;
    int span_x = c_hi - c_lo + 1;

    // stage: read maxima, hash, gather table feature per window cell
    int planebase = c_CUM[lvl] * NB + b * P * P;
    const float* T = tab + (size_t)lvl * 196608;
    float gmul = c_G[lvl];
    int n = span_y * span_x;
    for (int t = threadIdx.x; t < n; t += 256) {
        int r = t / span_x, c = t - r * span_x;
        int idx = planebase + (r_lo + r) * P + c_lo + c;
        float m0 = mws[idx];
        float m1 = mws[idx + CELLS_TOT];
        float m2 = mws[idx + 2 * CELLS_TOT];
        uint32_t g = hash3(m0, m1, m2, gmul);
        float3 tv = *(const float3*)(T + g * 3);
        float4 fv; fv.x = tv.x; fv.y = tv.y; fv.z = tv.z; fv.w = 0.f;
        s[t] = fv;
    }
    __syncthreads();

    int lane = threadIdx.x & 63;
    int w    = threadIdx.x >> 6;
    int xq   = lane & 15;
    int rg   = lane >> 4;
    int xb   = xt0 + xq * 4;

    int ix0t[4], ix1t[4]; float wx1t[4];
#pragma unroll
    for (int j = 0; j < 4; ++j) {
        int numx = (2 * (xb + j) + 1) * P - 256;
        int ix0  = numx >> 9;
        float fx = (float)(numx & 511) * (1.0f / 512.0f);
        int ix1;
        if (ix0 < 0)           { ix0 = 0;     ix1 = 0;     fx = 0.f; }
        else if (ix0 >= P - 1) { ix0 = P - 1; ix1 = P - 1; fx = 0.f; }
        else                   { ix1 = ix0 + 1; }
        ix0t[j] = ix0 - c_lo; ix1t[j] = ix1 - c_lo; wx1t[j] = fx;
    }

#pragma unroll
    for (int k = 0; k < 4; ++k) {
        int y = yt0 + w * 16 + rg * 4 + k;
        int numy = (2 * y + 1) * P - 256;
        int iy0  = numy >> 9;
        float fy = (float)(numy & 511) * (1.0f / 512.0f);
        int iy1;
        if (iy0 < 0)           { iy0 = 0;     iy1 = 0;     fy = 0.f; }
        else if (iy0 >= P - 1) { iy0 = P - 1; iy1 = P - 1; fy = 0.f; }
        else                   { iy1 = iy0 + 1; }
        const float4* p0 = s + (iy0 - r_lo) * span_x;
        const float4* p1 = s + (iy1 - r_lo) * span_x;
        float wy1 = fy, wy0 = 1.f - fy;

        float v[3][4];
#pragma unroll
        for (int j = 0; j < 4; ++j) {
            float wx1 = wx1t[j], wx0 = 1.f - wx1;
            float4 t00 = p0[ix0t[j]];
            float4 t01 = p0[ix1t[j]];
            float4 t10 = p1[ix0t[j]];
            float4 t11 = p1[ix1t[j]];
            v[0][j] = wy0 * (wx0 * t00.x + wx1 * t01.x) + wy1 * (wx0 * t10.x + wx1 * t11.x);
            v[1][j] = wy0 * (wx0 * t00.y + wx1 * t01.y) + wy1 * (wx0 * t10.y + wx1 * t11.y);
            v[2][j] = wy0 * (wx0 * t00.z + wx1 * t01.z) + wy1 * (wx0 * t10.z + wx1 * t11.z);
        }
        float* o = out + ((size_t)b * 48 + 3 * lvl) * 65536 + (size_t)y * 256 + xb;
#pragma unroll
        for (int c = 0; c < 3; ++c) {
            float4 q; q.x = v[c][0]; q.y = v[c][1]; q.z = v[c][2]; q.w = v[c][3];
            *(float4*)(o + (size_t)c * 65536) = q;
        }
    }
}

extern "C" void kernel_launch(void* const* d_in, const int* in_sizes, int n_in,
                              void* d_out, int out_size, void* d_ws, size_t ws_size,
                              hipStream_t stream)
{
    const float* img = (const float*)d_in[0];   // (16,3,256,256) f32
    const float* tab = (const float*)d_in[1];   // (16,65536,3) f32
    float* out = (float*)d_out;                 // (16,48,256,256) f32
    float* mws = (float*)d_ws;                  // 1,600,992 f32 = 6.4 MB

    (void)hipMemsetAsync(mws, 0, (size_t)MWS_FLOATS * sizeof(float), stream);
    hipLaunchKernelGGL(pool_direct,  dim3(K1_BLOCKS), dim3(256), 0, stream, img, tab, (unsigned int*)mws, out);
    hipLaunchKernelGGL(render_tiles, dim3(TILE_BLOCKS), dim3(256), 0, stream, tab, mws, out);
}